// Round 4
// baseline (43423.883 us; speedup 1.0000x reference)
//
#include <hip/hip_runtime.h>
#include <stdint.h>

#define T_STEPS 2048
#define HID 1024
#define G4 4096

typedef __attribute__((ext_vector_type(8))) short short8;
typedef __attribute__((ext_vector_type(4))) float float4v;

// ---------- ws layout ----------
// [0, 131072)              : h double buffer (2 x bf16[32][1024])
// [131072, 131584)         : flags (128 x u32), global-step monotonic
// [131584, 131588)         : dtype flag (1 = bf16 inputs, 0 = fp32 inputs)
// [135168, 266240)         : c state fp32 [32][1024] (persists across chunks)
// [0x100000, +TC*262144)   : x_proj bf16 chunk, [t_local][g][b]
#define HBUF_OFF 0ull
#define FLAG_OFF 131072ull
#define DT_OFF   131584ull
#define CST_OFF  135168ull
#define XP_OFF   0x100000ull

__device__ inline unsigned short f2bf(float f) {
  union { float f; unsigned int u; } v; v.f = f;
  unsigned int u = v.u;
  return (unsigned short)((u + 0x7fffu + ((u >> 16) & 1u)) >> 16);
}
__device__ inline float bf2f(unsigned short h) {
  union { unsigned int u; float f; } v; v.u = ((unsigned int)h) << 16;
  return v.f;
}
__device__ inline short8 pack8(float4 a, float4 b) {
  short8 r;
  r[0] = (short)f2bf(a.x); r[1] = (short)f2bf(a.y);
  r[2] = (short)f2bf(a.z); r[3] = (short)f2bf(a.w);
  r[4] = (short)f2bf(b.x); r[5] = (short)f2bf(b.y);
  r[6] = (short)f2bf(b.z); r[7] = (short)f2bf(b.w);
  return r;
}

// =====================================================================
// Dtype sniffer: W_ih ~ uniform(-2^-5, 2^-5). If stored bf16, every
// halfword's exp-field (bits 14:7) is in [100,123] (or exact 0). If fp32,
// only the high halfword of each pair matches (~54% overall).
// =====================================================================
__global__ void dtype_sniff(const unsigned short* __restrict__ w,
                            unsigned int* __restrict__ dt) {
  __shared__ int red[256];
  const int tid = threadIdx.x;
  int cnt = 0;
#pragma unroll
  for (int i = 0; i < 4; i++) {
    unsigned short h = w[tid * 4 + i];
    unsigned e = (h >> 7) & 0xFF;
    if (h == 0 || (e >= 100 && e <= 123)) cnt++;
  }
  red[tid] = cnt;
  __syncthreads();
  for (int s = 128; s > 0; s >>= 1) {
    if (tid < s) red[tid] += red[tid + s];
    __syncthreads();
  }
  if (tid == 0) dt[0] = (red[0] >= 922) ? 1u : 0u;   // 90% of 1024
}

// =====================================================================
// Phase A (per chunk): x_proj[tl][g][b] = x[b][t0+tl][:] . W_ih[g][:] + bias
// GEMM: M=TC*32 (m = tl*32+b), N=4096, K=1024. 128x128 tile, BK=32.
// Input dtype selected at runtime via dt flag; xp is always bf16.
// =====================================================================
__global__ __launch_bounds__(256) void xproj_gemm(
    const void* __restrict__ x, const void* __restrict__ Wih,
    const void* __restrict__ bih, const void* __restrict__ bhh,
    unsigned short* __restrict__ xp, int t0,
    const unsigned int* __restrict__ dt)
{
  __shared__ char smem[32768];           // As(10240)+Bs(10240); epilogue reuses all
  __shared__ float bias_s[128];
  unsigned short* As = (unsigned short*)smem;            // [128][40] (pad 32->40)
  unsigned short* Bs = (unsigned short*)(smem + 10240);

  const bool isbf = (*dt != 0);

  const int bid = blockIdx.x;
  // panel swizzle: panels of (16 m-tiles x 32 n-tiles) for L3 residency
  const int panel = bid >> 9;
  const int within = bid & 511;
  const int nt = within & 31;
  const int mt = (panel << 4) + (within >> 5);
  const int m0 = mt * 128;
  const int n0 = nt * 128;
  const int tl0 = m0 >> 5;               // 4 consecutive local t per tile

  const int tid = threadIdx.x;
  if (tid < 128) {
    bias_s[tid] = isbf
        ? bf2f(((const unsigned short*)bih)[n0 + tid]) +
          bf2f(((const unsigned short*)bhh)[n0 + tid])
        : ((const float*)bih)[n0 + tid] + ((const float*)bhh)[n0 + tid];
  }

  const int w = tid >> 6, lane = tid & 63;
  const int quad = lane >> 4, lr = lane & 15;
  const int wm = (w & 1) * 64, wn = (w >> 1) * 64;

  float4v acc[4][4];
#pragma unroll
  for (int i = 0; i < 4; i++)
#pragma unroll
    for (int j = 0; j < 4; j++) acc[i][j] = (float4v){0.f, 0.f, 0.f, 0.f};

  const int r = tid >> 1, half = tid & 1;
  // row m -> t = t0+tl0+(r>>5), b = r&31 ; x[b][t][k]
  const size_t aoff =
      ((size_t)(r & 31) * T_STEPS + (size_t)(t0 + tl0 + (r >> 5))) * HID + half * 16;
  const size_t boff = (size_t)(n0 + r) * HID + half * 16;
  unsigned short* adst = As + r * 40 + half * 16;
  unsigned short* bdst = Bs + r * 40 + half * 16;

  for (int k0 = 0; k0 < HID; k0 += 32) {
    __syncthreads();
    if (isbf) {
      const unsigned short* a16 = (const unsigned short*)x + aoff + k0;
      const unsigned short* b16 = (const unsigned short*)Wih + boff + k0;
      *(short8*)(adst)     = *(const short8*)(a16);
      *(short8*)(adst + 8) = *(const short8*)(a16 + 8);
      *(short8*)(bdst)     = *(const short8*)(b16);
      *(short8*)(bdst + 8) = *(const short8*)(b16 + 8);
    } else {
      const float4* af = (const float4*)((const float*)x + aoff + k0);
      const float4* bf = (const float4*)((const float*)Wih + boff + k0);
      float4 a0 = af[0], a1 = af[1], a2 = af[2], a3 = af[3];
      float4 b0 = bf[0], b1 = bf[1], b2 = bf[2], b3 = bf[3];
      *(short8*)(adst)     = pack8(a0, a1);
      *(short8*)(adst + 8) = pack8(a2, a3);
      *(short8*)(bdst)     = pack8(b0, b1);
      *(short8*)(bdst + 8) = pack8(b2, b3);
    }
    __syncthreads();
    short8 afr[4], bfr[4];
#pragma unroll
    for (int i = 0; i < 4; i++)
      afr[i] = *(const short8*)(As + (wm + i * 16 + lr) * 40 + quad * 8);
#pragma unroll
    for (int j = 0; j < 4; j++)
      bfr[j] = *(const short8*)(Bs + (wn + j * 16 + lr) * 40 + quad * 8);
#pragma unroll
    for (int i = 0; i < 4; i++)
#pragma unroll
      for (int j = 0; j < 4; j++)
        acc[i][j] = __builtin_amdgcn_mfma_f32_16x16x32_bf16(afr[i], bfr[j], acc[i][j], 0, 0, 0);
  }

  // epilogue: stage [tl][g][b] bf16 (32 KB) then coalesced copy
  __syncthreads();
  unsigned short* ep = (unsigned short*)smem;
#pragma unroll
  for (int i = 0; i < 4; i++)
#pragma unroll
    for (int j = 0; j < 4; j++)
#pragma unroll
      for (int rr = 0; rr < 4; rr++) {
        int ml = wm + i * 16 + quad * 4 + rr;
        int nl = wn + j * 16 + lr;
        float v = acc[i][j][rr] + bias_s[nl];
        ep[(((ml >> 5) * 128) + nl) * 32 + (ml & 31)] = f2bf(v);
      }
  __syncthreads();
#pragma unroll
  for (int tl = 0; tl < 4; tl++) {
    const uint4* s4 = (const uint4*)(smem + tl * 8192);
    uint4* d4 = (uint4*)(xp + ((size_t)(tl0 + tl) * G4 + n0) * 32);
    for (int i = tid; i < 512; i += 256) d4[i] = s4[i];
  }
}

// =====================================================================
// Phase R (per chunk): persistent LSTM recurrence, global steps [t0,t0+tc).
// 128 WGs x 256 thr, plain launch (128 blocks <= 256 CUs -> all resident).
// WG w owns h-cols [8w,8w+8); gate rows {q*1024+8w+j}. W_hh slice in regs;
// h double-buffered in ws (parity = global t); flags = global step count.
// =====================================================================
__global__ __launch_bounds__(256, 1) void lstm_rec(
    const void* __restrict__ Whh,
    const unsigned short* __restrict__ xp,
    unsigned short* __restrict__ hbuf,   // 2 x 32768 bf16
    unsigned int* __restrict__ flags,    // 128, global-step monotonic
    float* __restrict__ cstate,          // [32][1024] fp32, persists
    void* __restrict__ out,              // [h(32x1024) ; c(32x1024)]
    int t0, int tc,
    const unsigned int* __restrict__ dt)
{
  __shared__ unsigned short hs[32 * 520];   // half-K h tile [32][512] pad->520
  __shared__ float gbuf[32][33];
  __shared__ unsigned short hout[32][8];

  const bool isbf = (*dt != 0);
  const int wg = blockIdx.x;
  const int tid = threadIdx.x;
  const int w = tid >> 6, lane = tid & 63;
  const int quad = lane >> 4, lr = lane & 15;
  const int bt = w & 1, ct = w >> 1;

  // --- preload W_hh B-fragments into registers (bf16) ---
  short8 bfrag[32];
  {
    const int c = ct * 16 + lr;                          // local gate col 0..31
    const int grow = (c >> 3) * HID + 8 * wg + (c & 7);  // global gate row
    if (isbf) {
      const unsigned short* wrow = (const unsigned short*)Whh + (size_t)grow * HID;
#pragma unroll
      for (int s = 0; s < 32; s++)
        bfrag[s] = *(const short8*)(wrow + s * 32 + quad * 8);
    } else {
      const float* wrow = (const float*)Whh + (size_t)grow * HID;
#pragma unroll
      for (int s = 0; s < 32; s++) {
        float4 f0 = *(const float4*)(wrow + s * 32 + quad * 8);
        float4 f1 = *(const float4*)(wrow + s * 32 + quad * 8 + 4);
        bfrag[s] = pack8(f0, f1);
      }
    }
  }

  const int eb = tid & 31;   // batch for elementwise
  const int ej = tid >> 5;   // owned local h col 0..7
  const int gcol = 8 * wg + ej;
  float c_state = cstate[(size_t)eb * HID + gcol];
  long spin_budget = 50000000;

  for (int t = t0; t < t0 + tc; t++) {
    // ---- wait for all WGs to have published step t's h ----
    if (t > 0) {
      if (tid < 128) {
        const unsigned target = (unsigned)t;
        while (__hip_atomic_load(&flags[tid], __ATOMIC_RELAXED, __HIP_MEMORY_SCOPE_AGENT) < target) {
          if (--spin_budget < 0) break;
        }
      }
      __threadfence();
      __syncthreads();
    }

    // ---- GEMM: gates_hw[b][c] = sum_k h[b][k] * Whh[grow(c)][k] ----
    float4v acc = (float4v){0.f, 0.f, 0.f, 0.f};
    const unsigned long long* src =
        (const unsigned long long*)(hbuf + (size_t)(t & 1) * 32768);
#pragma unroll
    for (int kh = 0; kh < 2; kh++) {
      __syncthreads();  // hs safe to overwrite
      {
        const int c8 = tid & 127;
#pragma unroll
        for (int i = 0; i < 16; i++) {
          const int row = (i << 1) | (tid >> 7);
          unsigned long long v = __hip_atomic_load(
              src + (size_t)row * 256 + (size_t)kh * 128 + c8,
              __ATOMIC_RELAXED, __HIP_MEMORY_SCOPE_AGENT);
          *(unsigned long long*)((char*)hs + row * 1040 + c8 * 8) = v;
        }
      }
      __syncthreads();
      const unsigned short* arow = hs + (bt * 16 + lr) * 520 + quad * 8;
#pragma unroll
      for (int s = 0; s < 16; s++) {
        short8 af = *(const short8*)(arow + s * 32);
        acc = __builtin_amdgcn_mfma_f32_16x16x32_bf16(af, bfrag[kh * 16 + s], acc, 0, 0, 0);
      }
    }
#pragma unroll
    for (int rr = 0; rr < 4; rr++)
      gbuf[bt * 16 + quad * 4 + rr][ct * 16 + lr] = acc[rr];
    __syncthreads();

    // ---- elementwise LSTM cell (1 (b,col) pair per thread) ----
    {
      const unsigned short* xpt = xp + (size_t)(t - t0) * G4 * 32;
      float xi = bf2f(xpt[(size_t)(gcol) * 32 + eb]);
      float xf = bf2f(xpt[(size_t)(HID + gcol) * 32 + eb]);
      float xg = bf2f(xpt[(size_t)(2 * HID + gcol) * 32 + eb]);
      float xo = bf2f(xpt[(size_t)(3 * HID + gcol) * 32 + eb]);
      float gi = gbuf[eb][ej] + xi;
      float gf = gbuf[eb][8 + ej] + xf;
      float gg = gbuf[eb][16 + ej] + xg;
      float go = gbuf[eb][24 + ej] + xo;
      float si = 1.f / (1.f + __expf(-gi));
      float sf = 1.f / (1.f + __expf(-gf));
      float tg = tanhf(gg);
      float so = 1.f / (1.f + __expf(-go));
      c_state = sf * c_state + si * tg;
      float hn = so * tanhf(c_state);
      hout[eb][ej] = f2bf(hn);
      if (t == T_STEPS - 1) {
        if (isbf) {
          unsigned short* ob = (unsigned short*)out;
          ob[(size_t)eb * HID + gcol] = f2bf(hn);
          ob[32768 + (size_t)eb * HID + gcol] = f2bf(c_state);
        } else {
          float* of = (float*)out;
          of[(size_t)eb * HID + gcol] = hn;
          of[32768 + (size_t)eb * HID + gcol] = c_state;
        }
      }
    }
    __syncthreads();

    // ---- publish h_new slice (agent-scope stores) + release flag ----
    if (tid < 128) {
      const int b = tid >> 2, p = tid & 3;
      unsigned int v = *(const unsigned int*)(&hout[b][p * 2]);
      unsigned int* dst = (unsigned int*)(hbuf + (size_t)((t + 1) & 1) * 32768 +
                                          (size_t)b * HID + 8 * wg);
      __hip_atomic_store(dst + p, v, __ATOMIC_RELAXED, __HIP_MEMORY_SCOPE_AGENT);
    }
    __syncthreads();  // drains vmcnt -> all slice stores complete
    if (tid == 0)
      __hip_atomic_store(&flags[wg], (unsigned)(t + 1), __ATOMIC_RELEASE, __HIP_MEMORY_SCOPE_AGENT);
  }

  // persist c for the next chunk
  cstate[(size_t)eb * HID + gcol] = c_state;
}

extern "C" void kernel_launch(void* const* d_in, const int* in_sizes, int n_in,
                              void* d_out, int out_size, void* d_ws, size_t ws_size,
                              hipStream_t stream) {
  (void)in_sizes; (void)n_in; (void)out_size;
  const void* x   = d_in[0];
  const void* Wih = d_in[1];
  const void* Whh = d_in[2];
  const void* bih = d_in[3];
  const void* bhh = d_in[4];

  char* ws = (char*)d_ws;
  unsigned short* hbuf   = (unsigned short*)(ws + HBUF_OFF);
  unsigned int*   flags  = (unsigned int*)(ws + FLAG_OFF);
  unsigned int*   dt     = (unsigned int*)(ws + DT_OFF);
  float*          cstate = (float*)(ws + CST_OFF);
  unsigned short* xp     = (unsigned short*)(ws + XP_OFF);

  // Chunk length: largest power-of-two TC (16..2048) whose xp chunk fits ws.
  // xp chunk bytes = TC * 4096 * 32 * 2 = TC * 262144.
  int tc = 2048;
  while (tc > 16 && XP_OFF + (size_t)tc * 262144ull > ws_size) tc >>= 1;

  // zero h double-buffer + flags + dt + c state (ws is poisoned 0xAA)
  hipMemsetAsync(ws, 0, CST_OFF + 131072, stream);

  hipLaunchKernelGGL(dtype_sniff, dim3(1), dim3(256), 0, stream,
                     (const unsigned short*)Wih, dt);

  for (int t0 = 0; t0 < T_STEPS; t0 += tc) {
    hipLaunchKernelGGL(xproj_gemm, dim3(tc * 8), dim3(256), 0, stream,
                       x, Wih, bih, bhh, xp, t0, dt);
    hipLaunchKernelGGL(lstm_rec, dim3(128), dim3(256), 0, stream,
                       Whh, xp, hbuf, flags, cstate, d_out, t0, tc, dt);
  }
}

// Round 5
// 22414.738 us; speedup vs baseline: 1.9373x; 1.9373x over previous
//
#include <hip/hip_runtime.h>
#include <stdint.h>

#define T_STEPS 2048
#define HID 1024
#define G4 4096

typedef __attribute__((ext_vector_type(8))) short short8;
typedef __attribute__((ext_vector_type(4))) float float4v;

// ---------- ws layout ----------
// [0, 131072)              : h double buffer (2 x bf16[32][1024])
// [131072, 131584)         : flags (128 x u32), global-step monotonic
// [131584, 131588)         : dtype flag (1 = bf16 inputs, 0 = fp32 inputs)
// [135168, 266240)         : c state fp32 [32][1024] (persists across chunks)
// [0x100000, +TC*262144)   : x_proj bf16 chunk, [t_local][g][b]
#define HBUF_OFF 0ull
#define FLAG_OFF 131072ull
#define DT_OFF   131584ull
#define CST_OFF  135168ull
#define XP_OFF   0x100000ull

__device__ inline unsigned short f2bf(float f) {
  union { float f; unsigned int u; } v; v.f = f;
  unsigned int u = v.u;
  return (unsigned short)((u + 0x7fffu + ((u >> 16) & 1u)) >> 16);
}
__device__ inline float bf2f(unsigned short h) {
  union { unsigned int u; float f; } v; v.u = ((unsigned int)h) << 16;
  return v.f;
}
__device__ inline short8 pack8(float4 a, float4 b) {
  short8 r;
  r[0] = (short)f2bf(a.x); r[1] = (short)f2bf(a.y);
  r[2] = (short)f2bf(a.z); r[3] = (short)f2bf(a.w);
  r[4] = (short)f2bf(b.x); r[5] = (short)f2bf(b.y);
  r[6] = (short)f2bf(b.z); r[7] = (short)f2bf(b.w);
  return r;
}

// =====================================================================
// Dtype sniffer: W_ih ~ uniform(-2^-5, 2^-5). If stored bf16, every
// halfword's exp-field (bits 14:7) is in [100,123] (or exact 0). If fp32,
// only high halfwords match (~54%).
// =====================================================================
__global__ void dtype_sniff(const unsigned short* __restrict__ w,
                            unsigned int* __restrict__ dt) {
  __shared__ int red[256];
  const int tid = threadIdx.x;
  int cnt = 0;
#pragma unroll
  for (int i = 0; i < 4; i++) {
    unsigned short h = w[tid * 4 + i];
    unsigned e = (h >> 7) & 0xFF;
    if (h == 0 || (e >= 100 && e <= 123)) cnt++;
  }
  red[tid] = cnt;
  __syncthreads();
  for (int s = 128; s > 0; s >>= 1) {
    if (tid < s) red[tid] += red[tid + s];
    __syncthreads();
  }
  if (tid == 0) dt[0] = (red[0] >= 922) ? 1u : 0u;   // 90% of 1024
}

// =====================================================================
// Phase A (per chunk): x_proj[tl][g][b] = x[b][t0+tl][:] . W_ih[g][:] + bias
// GEMM: M=TC*32 (m = tl*32+b), N=4096, K=1024. 128x128 tile, BK=32.
// =====================================================================
__global__ __launch_bounds__(256) void xproj_gemm(
    const void* __restrict__ x, const void* __restrict__ Wih,
    const void* __restrict__ bih, const void* __restrict__ bhh,
    unsigned short* __restrict__ xp, int t0,
    const unsigned int* __restrict__ dt)
{
  __shared__ char smem[32768];           // As(10240)+Bs(10240); epilogue reuses all
  __shared__ float bias_s[128];
  unsigned short* As = (unsigned short*)smem;            // [128][40] (pad 32->40)
  unsigned short* Bs = (unsigned short*)(smem + 10240);

  const bool isbf = (*dt != 0);

  const int bid = blockIdx.x;
  const int panel = bid >> 9;
  const int within = bid & 511;
  const int nt = within & 31;
  const int mt = (panel << 4) + (within >> 5);
  const int m0 = mt * 128;
  const int n0 = nt * 128;
  const int tl0 = m0 >> 5;               // 4 consecutive local t per tile

  const int tid = threadIdx.x;
  if (tid < 128) {
    bias_s[tid] = isbf
        ? bf2f(((const unsigned short*)bih)[n0 + tid]) +
          bf2f(((const unsigned short*)bhh)[n0 + tid])
        : ((const float*)bih)[n0 + tid] + ((const float*)bhh)[n0 + tid];
  }

  const int w = tid >> 6, lane = tid & 63;
  const int quad = lane >> 4, lr = lane & 15;
  const int wm = (w & 1) * 64, wn = (w >> 1) * 64;

  float4v acc[4][4];
#pragma unroll
  for (int i = 0; i < 4; i++)
#pragma unroll
    for (int j = 0; j < 4; j++) acc[i][j] = (float4v){0.f, 0.f, 0.f, 0.f};

  const int r = tid >> 1, half = tid & 1;
  const size_t aoff =
      ((size_t)(r & 31) * T_STEPS + (size_t)(t0 + tl0 + (r >> 5))) * HID + half * 16;
  const size_t boff = (size_t)(n0 + r) * HID + half * 16;
  unsigned short* adst = As + r * 40 + half * 16;
  unsigned short* bdst = Bs + r * 40 + half * 16;

  for (int k0 = 0; k0 < HID; k0 += 32) {
    __syncthreads();
    if (isbf) {
      const unsigned short* a16 = (const unsigned short*)x + aoff + k0;
      const unsigned short* b16 = (const unsigned short*)Wih + boff + k0;
      *(short8*)(adst)     = *(const short8*)(a16);
      *(short8*)(adst + 8) = *(const short8*)(a16 + 8);
      *(short8*)(bdst)     = *(const short8*)(b16);
      *(short8*)(bdst + 8) = *(const short8*)(b16 + 8);
    } else {
      const float4* af = (const float4*)((const float*)x + aoff + k0);
      const float4* bf = (const float4*)((const float*)Wih + boff + k0);
      float4 a0 = af[0], a1 = af[1], a2 = af[2], a3 = af[3];
      float4 b0 = bf[0], b1 = bf[1], b2 = bf[2], b3 = bf[3];
      *(short8*)(adst)     = pack8(a0, a1);
      *(short8*)(adst + 8) = pack8(a2, a3);
      *(short8*)(bdst)     = pack8(b0, b1);
      *(short8*)(bdst + 8) = pack8(b2, b3);
    }
    __syncthreads();
    short8 afr[4], bfr[4];
#pragma unroll
    for (int i = 0; i < 4; i++)
      afr[i] = *(const short8*)(As + (wm + i * 16 + lr) * 40 + quad * 8);
#pragma unroll
    for (int j = 0; j < 4; j++)
      bfr[j] = *(const short8*)(Bs + (wn + j * 16 + lr) * 40 + quad * 8);
#pragma unroll
    for (int i = 0; i < 4; i++)
#pragma unroll
      for (int j = 0; j < 4; j++)
        acc[i][j] = __builtin_amdgcn_mfma_f32_16x16x32_bf16(afr[i], bfr[j], acc[i][j], 0, 0, 0);
  }

  __syncthreads();
  unsigned short* ep = (unsigned short*)smem;
#pragma unroll
  for (int i = 0; i < 4; i++)
#pragma unroll
    for (int j = 0; j < 4; j++)
#pragma unroll
      for (int rr = 0; rr < 4; rr++) {
        int ml = wm + i * 16 + quad * 4 + rr;
        int nl = wn + j * 16 + lr;
        float v = acc[i][j][rr] + bias_s[nl];
        ep[(((ml >> 5) * 128) + nl) * 32 + (ml & 31)] = f2bf(v);
      }
  __syncthreads();
#pragma unroll
  for (int tl = 0; tl < 4; tl++) {
    const uint4* s4 = (const uint4*)(smem + tl * 8192);
    uint4* d4 = (uint4*)(xp + ((size_t)(tl0 + tl) * G4 + n0) * 32);
    for (int i = tid; i < 512; i += 256) d4[i] = s4[i];
  }
}

// =====================================================================
// Phase R (per chunk): persistent LSTM recurrence, global steps [t0,t0+tc).
// 128 WGs x 256 thr. WG w owns h-cols [8w,8w+8) = gate rows {q*1024+8w+j}.
// W_hh slice in regs; h double-buffered in ws (parity = t&1); flags are
// global-step monotonic. NO __threadfence: h/flag traffic uses per-access
// agent-scope atomics (cache-bypass), producer drains vmcnt via the
// pre-flag __syncthreads, consumer orders h-loads after the spin via
// __syncthreads. This avoids per-step L2 writeback/invalidate.
// =====================================================================
__global__ __launch_bounds__(256, 1) void lstm_rec(
    const void* __restrict__ Whh,
    const unsigned short* __restrict__ xp,
    unsigned short* __restrict__ hbuf,   // 2 x 32768 bf16
    unsigned int* __restrict__ flags,    // 128, global-step monotonic
    float* __restrict__ cstate,          // [32][1024] fp32, persists
    void* __restrict__ out,              // [h(32x1024) ; c(32x1024)]
    int t0, int tc,
    const unsigned int* __restrict__ dt)
{
  __shared__ unsigned short hs[32 * 1032];  // full h tile [32][1024], pad->1032
  __shared__ float gbuf[32][33];
  __shared__ unsigned short hout[32][8];

  const bool isbf = (*dt != 0);
  const int wg = blockIdx.x;
  const int tid = threadIdx.x;
  const int w = tid >> 6, lane = tid & 63;
  const int quad = lane >> 4, lr = lane & 15;
  const int bt = w & 1, ct = w >> 1;

  // --- preload W_hh B-fragments into registers (bf16) ---
  short8 bfrag[32];
  {
    const int c = ct * 16 + lr;                          // local gate col 0..31
    const int grow = (c >> 3) * HID + 8 * wg + (c & 7);  // global gate row
    if (isbf) {
      const unsigned short* wrow = (const unsigned short*)Whh + (size_t)grow * HID;
#pragma unroll
      for (int s = 0; s < 32; s++)
        bfrag[s] = *(const short8*)(wrow + s * 32 + quad * 8);
    } else {
      const float* wrow = (const float*)Whh + (size_t)grow * HID;
#pragma unroll
      for (int s = 0; s < 32; s++) {
        float4 f0 = *(const float4*)(wrow + s * 32 + quad * 8);
        float4 f1 = *(const float4*)(wrow + s * 32 + quad * 8 + 4);
        bfrag[s] = pack8(f0, f1);
      }
    }
  }

  const int eb = tid & 31;   // batch for elementwise
  const int ej = tid >> 5;   // owned local h col 0..7
  const int gcol = 8 * wg + ej;
  float c_state = cstate[(size_t)eb * HID + gcol];
  long spin_budget = 50000000;

  for (int t = t0; t < t0 + tc; t++) {
    // ---- prefetch xp gate values (no dependence on flags; hides HBM lat)
    const unsigned short* xpt = xp + (size_t)(t - t0) * (G4 * 32);
    unsigned short rxi = xpt[(size_t)(gcol) * 32 + eb];
    unsigned short rxf = xpt[(size_t)(HID + gcol) * 32 + eb];
    unsigned short rxg = xpt[(size_t)(2 * HID + gcol) * 32 + eb];
    unsigned short rxo = xpt[(size_t)(3 * HID + gcol) * 32 + eb];

    // ---- wait for all WGs to have published step t's h ----
    if (t > 0) {
      if (tid < 128) {
        const unsigned target = (unsigned)t;
        while (__hip_atomic_load(&flags[tid], __ATOMIC_RELAXED, __HIP_MEMORY_SCOPE_AGENT) < target) {
          if (--spin_budget < 0) break;
        }
      }
      __syncthreads();   // orders all waves' h-loads after the spin
    }

    // ---- stage full h tile (64 KB) in one shot: 32 x 8B per thread ----
    {
      const unsigned long long* src =
          (const unsigned long long*)(hbuf + (size_t)(t & 1) * 32768);
#pragma unroll
      for (int i = 0; i < 32; i++) {
        const int idx = i * 256 + tid;         // 0..8191 ull
        const int row = idx >> 8, pos = idx & 255;
        unsigned long long v = __hip_atomic_load(
            src + idx, __ATOMIC_RELAXED, __HIP_MEMORY_SCOPE_AGENT);
        *(unsigned long long*)((char*)hs + row * 2064 + pos * 8) = v;
      }
    }
    __syncthreads();

    // ---- GEMM: gates_hw[b][c] = sum_k h[b][k]*Whh[grow(c)][k]; 2 acc chains
    float4v acc0 = (float4v){0.f, 0.f, 0.f, 0.f};
    float4v acc1 = (float4v){0.f, 0.f, 0.f, 0.f};
    {
      const unsigned short* arow = hs + (bt * 16 + lr) * 1032 + quad * 8;
#pragma unroll
      for (int s = 0; s < 16; s++) {
        short8 a0 = *(const short8*)(arow + (2 * s) * 32);
        short8 a1 = *(const short8*)(arow + (2 * s + 1) * 32);
        acc0 = __builtin_amdgcn_mfma_f32_16x16x32_bf16(a0, bfrag[2 * s], acc0, 0, 0, 0);
        acc1 = __builtin_amdgcn_mfma_f32_16x16x32_bf16(a1, bfrag[2 * s + 1], acc1, 0, 0, 0);
      }
    }
#pragma unroll
    for (int rr = 0; rr < 4; rr++)
      gbuf[bt * 16 + quad * 4 + rr][ct * 16 + lr] = acc0[rr] + acc1[rr];
    __syncthreads();

    // ---- elementwise LSTM cell (1 (b,col) pair per thread) ----
    {
      float gi = gbuf[eb][ej] + bf2f(rxi);
      float gf = gbuf[eb][8 + ej] + bf2f(rxf);
      float gg = gbuf[eb][16 + ej] + bf2f(rxg);
      float go = gbuf[eb][24 + ej] + bf2f(rxo);
      float si = 1.f / (1.f + __expf(-gi));
      float sf = 1.f / (1.f + __expf(-gf));
      float tg = tanhf(gg);
      float so = 1.f / (1.f + __expf(-go));
      c_state = sf * c_state + si * tg;
      float hn = so * tanhf(c_state);
      hout[eb][ej] = f2bf(hn);
      if (t == T_STEPS - 1) {
        if (isbf) {
          unsigned short* ob = (unsigned short*)out;
          ob[(size_t)eb * HID + gcol] = f2bf(hn);
          ob[32768 + (size_t)eb * HID + gcol] = f2bf(c_state);
        } else {
          float* of = (float*)out;
          of[(size_t)eb * HID + gcol] = hn;
          of[32768 + (size_t)eb * HID + gcol] = c_state;
        }
      }
    }
    __syncthreads();

    // ---- publish h_new slice (agent-scope, cache-bypass) + release flag ----
    if (tid < 32) {
      const unsigned long long* hv = (const unsigned long long*)&hout[tid][0];
      unsigned long long* dst =
          (unsigned long long*)(hbuf + (size_t)((t + 1) & 1) * 32768 +
                                (size_t)tid * HID + 8 * wg);
      __hip_atomic_store(dst, hv[0], __ATOMIC_RELAXED, __HIP_MEMORY_SCOPE_AGENT);
      __hip_atomic_store(dst + 1, hv[1], __ATOMIC_RELAXED, __HIP_MEMORY_SCOPE_AGENT);
    }
    __syncthreads();  // drains vmcnt -> slice stores complete before flag
    if (tid == 0)
      __hip_atomic_store(&flags[wg], (unsigned)(t + 1), __ATOMIC_RELAXED, __HIP_MEMORY_SCOPE_AGENT);
  }

  // persist c for the next chunk
  cstate[(size_t)eb * HID + gcol] = c_state;
}

extern "C" void kernel_launch(void* const* d_in, const int* in_sizes, int n_in,
                              void* d_out, int out_size, void* d_ws, size_t ws_size,
                              hipStream_t stream) {
  (void)in_sizes; (void)n_in; (void)out_size;
  const void* x   = d_in[0];
  const void* Wih = d_in[1];
  const void* Whh = d_in[2];
  const void* bih = d_in[3];
  const void* bhh = d_in[4];

  char* ws = (char*)d_ws;
  unsigned short* hbuf   = (unsigned short*)(ws + HBUF_OFF);
  unsigned int*   flags  = (unsigned int*)(ws + FLAG_OFF);
  unsigned int*   dt     = (unsigned int*)(ws + DT_OFF);
  float*          cstate = (float*)(ws + CST_OFF);
  unsigned short* xp     = (unsigned short*)(ws + XP_OFF);

  int tc = 2048;
  while (tc > 16 && XP_OFF + (size_t)tc * 262144ull > ws_size) tc >>= 1;

  hipMemsetAsync(ws, 0, CST_OFF + 131072, stream);

  hipLaunchKernelGGL(dtype_sniff, dim3(1), dim3(256), 0, stream,
                     (const unsigned short*)Wih, dt);

  for (int t0 = 0; t0 < T_STEPS; t0 += tc) {
    hipLaunchKernelGGL(xproj_gemm, dim3(tc * 8), dim3(256), 0, stream,
                       x, Wih, bih, bhh, xp, t0, dt);
    hipLaunchKernelGGL(lstm_rec, dim3(128), dim3(256), 0, stream,
                       Whh, xp, hbuf, flags, cstate, d_out, t0, tc, dt);
  }
}